// Round 3
// baseline (39.052 us; speedup 1.0000x reference)
//
#include <hip/hip_runtime.h>
#include <math.h>

#define N_PTS 512
#define W_IMG 256
#define H_IMG 256
#define NPIX (W_IMG * H_IMG)
#define NSEG 4
#define SEG_LEN (N_PTS / NSEG)

// ws layout: float4 PK0[512] | PK1[512] | PK2[512]
//   PK0 = (U, V, -0.5a, -b)   PK1 = (-0.5c, PT, AL, D)   PK2 = (PR, PG, PB, 0)

__global__ __launch_bounds__(N_PTS) void prep_kernel(
    const float* __restrict__ pc,      // N x 3
    const float* __restrict__ q,       // 1 x 4  (x,y,z,w)
    const float* __restrict__ t,       // 1 x 3
    const float* __restrict__ K,       // 3 x 3 row-major
    const float* __restrict__ color,   // N x 3
    const float* __restrict__ alpha,   // N
    const float* __restrict__ conic,   // N x 3 (a,b,c)
    float4* __restrict__ ws4)
{
    __shared__ float sd[N_PTS];
    const int tid = threadIdx.x;

    const float qx = q[0], qy = q[1], qz = q[2], qw = q[3];
    const float R00 = 1.f - 2.f * (qy * qy + qz * qz);
    const float R01 = 2.f * (qx * qy - qz * qw);
    const float R02 = 2.f * (qx * qz + qy * qw);
    const float R10 = 2.f * (qx * qy + qz * qw);
    const float R11 = 1.f - 2.f * (qx * qx + qz * qz);
    const float R12 = 2.f * (qy * qz - qx * qw);
    const float R20 = 2.f * (qx * qz - qy * qw);
    const float R21 = 2.f * (qy * qz + qx * qw);
    const float R22 = 1.f - 2.f * (qx * qx + qy * qy);
    const float tx = t[0], ty = t[1], tz = t[2];

    const float px = pc[tid * 3 + 0], py = pc[tid * 3 + 1], pz = pc[tid * 3 + 2];
    const float cxp = R00 * px + R01 * py + R02 * pz + tx;
    const float cyp = R10 * px + R11 * py + R12 * pz + ty;
    const float czp = R20 * px + R21 * py + R22 * pz + tz;

    sd[tid] = czp;
    __syncthreads();

    // stable argsort rank: #{j : d_j < d_i || (d_j == d_i && j < i)}
    int rank = 0;
    const float4* sd4 = (const float4*)sd;
    #pragma unroll 4
    for (int j4 = 0; j4 < N_PTS / 4; ++j4) {
        const float4 v = sd4[j4];           // uniform addr -> LDS broadcast
        const int jb = j4 * 4;
        rank += (v.x < czp) || (v.x == czp && (jb + 0) < tid);
        rank += (v.y < czp) || (v.y == czp && (jb + 1) < tid);
        rank += (v.z < czp) || (v.z == czp && (jb + 2) < tid);
        rank += (v.w < czp) || (v.w == czp && (jb + 3) < tid);
    }

    const float fx = K[0], fy = K[4], cu = K[2], cv = K[5];
    const float al = alpha[tid];
    const float u  = cxp * fx / czp + cu;
    const float v  = cyp * fy / czp + cv;
    // prune threshold: contribution zero iff exp(pw)*al < 1/255, i.e.
    // pw < -log(255*al). Margin 0.01 so float boundary cases take exact path.
    const float pt = -__logf(255.0f * al) - 0.01f;

    ws4[rank]             = make_float4(u, v, -0.5f * conic[tid * 3 + 0],
                                        -conic[tid * 3 + 1]);
    ws4[N_PTS + rank]     = make_float4(-0.5f * conic[tid * 3 + 2], pt, al, czp);
    ws4[2 * N_PTS + rank] = make_float4(color[tid * 3 + 0], color[tid * 3 + 1],
                                        color[tid * 3 + 2], 0.f);
}

__global__ __launch_bounds__(256) void raster_kernel(
    const float4* __restrict__ ws4,
    float* __restrict__ out)
{
    const int tid  = threadIdx.x;
    const int lane = tid & 63;
    // force wave-uniform segment id into an SGPR so point loads scalarize
    const int seg  = __builtin_amdgcn_readfirstlane(tid >> 6);

    // 8x8 pixel tile per wave (all 4 waves of a block share the tile)
    const int tile = blockIdx.x;                 // 0..1023
    const int px = ((tile & 31) << 3) + (lane & 7);
    const int py = ((tile >> 5) << 3) + (lane >> 3);
    const float up = (float)px + 0.5f;
    const float vp = (float)py + 0.5f;

    const float4* __restrict__ PK0 = ws4;
    const float4* __restrict__ PK1 = ws4 + N_PTS;
    const float4* __restrict__ PK2 = ws4 + 2 * N_PTS;

    float T = 1.f, rr = 0.f, gg = 0.f, bb = 0.f, dd = 0.f, aa = 0.f;

    const int n0 = seg * SEG_LEN;
    #pragma unroll 4
    for (int i = 0; i < SEG_LEN; ++i) {
        const int n = n0 + i;                    // wave-uniform -> s_load
        const float4 p0 = PK0[n];                // U V A' B'
        const float4 p1 = PK1[n];                // C' PT AL D
        const float dx = up - p0.x;
        const float dy = vp - p0.y;
        const float pw = fmaf(p0.z, dx * dx,
                         fmaf(p1.x, dy * dy, p0.w * (dx * dy)));
        if (__any(pw >= p1.y)) {
            const float pa = __expf(pw) * p1.z;
            // pw < PT implies pa < e^-0.01/255 < 1/255, so pa test is exact
            const float alEff = (pa >= (1.0f / 255.0f)) ? fminf(pa, 0.99f) : 0.f;
            const float w = alEff * T;
            const float4 p2 = PK2[n];            // PR PG PB
            rr = fmaf(w, p2.x, rr);
            gg = fmaf(w, p2.y, gg);
            bb = fmaf(w, p2.z, bb);
            dd = fmaf(w, p1.w, dd);
            aa += w;
            T = fmaf(-alEff, T, T);              // T *= (1 - alEff)
        }
    }

    // ordered combine of the 4 depth segments: (c,T) = (c0 + T0*c1, T0*T1) ...
    __shared__ float part[NSEG][6][64];
    part[seg][0][lane] = rr;
    part[seg][1][lane] = gg;
    part[seg][2][lane] = bb;
    part[seg][3][lane] = dd;
    part[seg][4][lane] = aa;
    part[seg][5][lane] = T;
    __syncthreads();

    if (tid < 64) {
        float c0 = part[0][0][tid], c1 = part[0][1][tid], c2 = part[0][2][tid];
        float c3 = part[0][3][tid], c4 = part[0][4][tid];
        float Tacc = part[0][5][tid];
        #pragma unroll
        for (int s = 1; s < NSEG; ++s) {
            c0 = fmaf(Tacc, part[s][0][tid], c0);
            c1 = fmaf(Tacc, part[s][1][tid], c1);
            c2 = fmaf(Tacc, part[s][2][tid], c2);
            c3 = fmaf(Tacc, part[s][3][tid], c3);
            c4 = fmaf(Tacc, part[s][4][tid], c4);
            Tacc *= part[s][5][tid];
        }
        const int opx = ((tile & 31) << 3) + (tid & 7);
        const int opy = ((tile >> 5) << 3) + (tid >> 3);
        const int p = opy * W_IMG + opx;
        out[p * 3 + 0] = c0;
        out[p * 3 + 1] = c1;
        out[p * 3 + 2] = c2;
        out[NPIX * 3 + p] = c3;
        out[NPIX * 4 + p] = c4;
    }
}

extern "C" void kernel_launch(void* const* d_in, const int* in_sizes, int n_in,
                              void* d_out, int out_size, void* d_ws, size_t ws_size,
                              hipStream_t stream) {
    const float* pc    = (const float*)d_in[0];
    const float* q     = (const float*)d_in[1];
    const float* t     = (const float*)d_in[2];
    const float* K     = (const float*)d_in[3];
    const float* color = (const float*)d_in[4];
    const float* alpha = (const float*)d_in[5];
    const float* conic = (const float*)d_in[6];
    float* out  = (float*)d_out;
    float4* ws4 = (float4*)d_ws;

    prep_kernel<<<1, N_PTS, 0, stream>>>(pc, q, t, K, color, alpha, conic, ws4);
    raster_kernel<<<NPIX / 64, 256, 0, stream>>>(ws4, out);
}

// Round 4
// 31.172 us; speedup vs baseline: 1.2528x; 1.2528x over previous
//
#include <hip/hip_runtime.h>
#include <math.h>

#define N_PTS 512
#define W_IMG 256
#define H_IMG 256
#define NPIX (W_IMG * H_IMG)
#define NSEG 8
#define SEG_LEN (N_PTS / NSEG)

// ws layout: float4 PK0[512] | PK1[512] | PK2[512]
//   PK0 = (U, V, -0.5a, -b)   PK1 = (-0.5c, PT, AL, D)   PK2 = (PR, PG, PB, 0)

__global__ __launch_bounds__(N_PTS) void prep_kernel(
    const float* __restrict__ pc,      // N x 3
    const float* __restrict__ q,       // 1 x 4  (x,y,z,w)
    const float* __restrict__ t,       // 1 x 3
    const float* __restrict__ K,       // 3 x 3 row-major
    const float* __restrict__ color,   // N x 3
    const float* __restrict__ alpha,   // N
    const float* __restrict__ conic,   // N x 3 (a,b,c)
    float4* __restrict__ ws4)
{
    __shared__ float sd[N_PTS];
    const int tid = threadIdx.x;

    const float qx = q[0], qy = q[1], qz = q[2], qw = q[3];
    const float R00 = 1.f - 2.f * (qy * qy + qz * qz);
    const float R01 = 2.f * (qx * qy - qz * qw);
    const float R02 = 2.f * (qx * qz + qy * qw);
    const float R10 = 2.f * (qx * qy + qz * qw);
    const float R11 = 1.f - 2.f * (qx * qx + qz * qz);
    const float R12 = 2.f * (qy * qz - qx * qw);
    const float R20 = 2.f * (qx * qz - qy * qw);
    const float R21 = 2.f * (qy * qz + qx * qw);
    const float R22 = 1.f - 2.f * (qx * qx + qy * qy);
    const float tx = t[0], ty = t[1], tz = t[2];

    const float px = pc[tid * 3 + 0], py = pc[tid * 3 + 1], pz = pc[tid * 3 + 2];
    const float cxp = R00 * px + R01 * py + R02 * pz + tx;
    const float cyp = R10 * px + R11 * py + R12 * pz + ty;
    const float czp = R20 * px + R21 * py + R22 * pz + tz;

    sd[tid] = czp;
    __syncthreads();

    // stable argsort rank: #{j : d_j < d_i || (d_j == d_i && j < i)}
    int rank = 0;
    const float4* sd4 = (const float4*)sd;
    #pragma unroll 4
    for (int j4 = 0; j4 < N_PTS / 4; ++j4) {
        const float4 v = sd4[j4];           // uniform addr -> LDS broadcast
        const int jb = j4 * 4;
        rank += (v.x < czp) || (v.x == czp && (jb + 0) < tid);
        rank += (v.y < czp) || (v.y == czp && (jb + 1) < tid);
        rank += (v.z < czp) || (v.z == czp && (jb + 2) < tid);
        rank += (v.w < czp) || (v.w == czp && (jb + 3) < tid);
    }

    const float fx = K[0], fy = K[4], cu = K[2], cv = K[5];
    const float al = alpha[tid];
    const float u  = cxp * fx / czp + cu;
    const float v  = cyp * fy / czp + cv;
    // prune threshold: contribution zero iff exp(pw)*al < 1/255, i.e.
    // pw < -log(255*al). Margin 0.01 so float boundary cases take exact path.
    const float pt = -__logf(255.0f * al) - 0.01f;

    ws4[rank]             = make_float4(u, v, -0.5f * conic[tid * 3 + 0],
                                        -conic[tid * 3 + 1]);
    ws4[N_PTS + rank]     = make_float4(-0.5f * conic[tid * 3 + 2], pt, al, czp);
    ws4[2 * N_PTS + rank] = make_float4(color[tid * 3 + 0], color[tid * 3 + 1],
                                        color[tid * 3 + 2], 0.f);
}

__global__ __launch_bounds__(512, 8) void raster_kernel(
    const float4* __restrict__ ws4,
    float* __restrict__ out)
{
    const int tid  = threadIdx.x;
    const int lane = tid & 63;
    // force wave-uniform segment id into an SGPR so point loads scalarize
    const int seg  = __builtin_amdgcn_readfirstlane(tid >> 6);

    const int pix = blockIdx.x * 64 + lane;          // 64 consecutive px / row
    const float up = (float)(pix & (W_IMG - 1)) + 0.5f;
    const float vp = (float)(pix >> 8) + 0.5f;

    const float4* __restrict__ PK0 = ws4;
    const float4* __restrict__ PK1 = ws4 + N_PTS;
    const float4* __restrict__ PK2 = ws4 + 2 * N_PTS;

    float T = 1.f, rr = 0.f, gg = 0.f, bb = 0.f, dd = 0.f, aa = 0.f;

    const int n0 = seg * SEG_LEN;
    #pragma unroll 4
    for (int i = 0; i < SEG_LEN; ++i) {
        const int n = n0 + i;                    // wave-uniform -> s_load
        const float4 p0 = PK0[n];                // U V A' B'
        const float4 p1 = PK1[n];                // C' PT AL D
        const float4 p2 = PK2[n];                // PR PG PB (unconditional: lets
                                                 // the scheduler batch s_loads)
        const float dx = up - p0.x;
        const float dy = vp - p0.y;
        const float pw = fmaf(p0.z, dx * dx,
                         fmaf(p1.x, dy * dy, p0.w * (dx * dy)));
        if (__any(pw >= p1.y)) {
            const float pa = __expf(pw) * p1.z;
            // pw < PT implies pa < e^-0.01/255 < 1/255, so pa test is exact
            const float alEff = (pa >= (1.0f / 255.0f)) ? fminf(pa, 0.99f) : 0.f;
            const float w = alEff * T;
            rr = fmaf(w, p2.x, rr);
            gg = fmaf(w, p2.y, gg);
            bb = fmaf(w, p2.z, bb);
            dd = fmaf(w, p1.w, dd);
            aa += w;
            T = fmaf(-alEff, T, T);              // T *= (1 - alEff)
        }
    }

    // ordered combine of the 8 depth segments: (c,T) = (c0 + T0*c1, T0*T1) ...
    __shared__ float part[NSEG][6][64];
    part[seg][0][lane] = rr;
    part[seg][1][lane] = gg;
    part[seg][2][lane] = bb;
    part[seg][3][lane] = dd;
    part[seg][4][lane] = aa;
    part[seg][5][lane] = T;
    __syncthreads();

    if (tid < 64) {
        float c0 = part[0][0][tid], c1 = part[0][1][tid], c2 = part[0][2][tid];
        float c3 = part[0][3][tid], c4 = part[0][4][tid];
        float Tacc = part[0][5][tid];
        #pragma unroll
        for (int s = 1; s < NSEG; ++s) {
            c0 = fmaf(Tacc, part[s][0][tid], c0);
            c1 = fmaf(Tacc, part[s][1][tid], c1);
            c2 = fmaf(Tacc, part[s][2][tid], c2);
            c3 = fmaf(Tacc, part[s][3][tid], c3);
            c4 = fmaf(Tacc, part[s][4][tid], c4);
            Tacc *= part[s][5][tid];
        }
        const int p = blockIdx.x * 64 + tid;
        out[p * 3 + 0] = c0;
        out[p * 3 + 1] = c1;
        out[p * 3 + 2] = c2;
        out[NPIX * 3 + p] = c3;
        out[NPIX * 4 + p] = c4;
    }
}

extern "C" void kernel_launch(void* const* d_in, const int* in_sizes, int n_in,
                              void* d_out, int out_size, void* d_ws, size_t ws_size,
                              hipStream_t stream) {
    const float* pc    = (const float*)d_in[0];
    const float* q     = (const float*)d_in[1];
    const float* t     = (const float*)d_in[2];
    const float* K     = (const float*)d_in[3];
    const float* color = (const float*)d_in[4];
    const float* alpha = (const float*)d_in[5];
    const float* conic = (const float*)d_in[6];
    float* out  = (float*)d_out;
    float4* ws4 = (float4*)d_ws;

    prep_kernel<<<1, N_PTS, 0, stream>>>(pc, q, t, K, color, alpha, conic, ws4);
    raster_kernel<<<NPIX / 64, 512, 0, stream>>>(ws4, out);
}